// Round 8
// baseline (97.400 us; speedup 1.0000x reference)
//
#include <hip/hip_runtime.h>
#include <math.h>

#define PH 7
#define PW 7
#define BB 4
#define HH 64
#define WW 64
#define CC 256
#define RR 128
#define CH4 (CC / 4)                   // 64 float4 per pixel
#define BINS_PER_IMG (RR * PH * PW)    // 6272
#define NBINS (BB * BINS_PER_IMG)      // 25088
#define DESC_BYTES ((size_t)NBINS * 16)
#define MAIN_BLK 3136                  // 12544 waves, 2 bins/wave
#define WAVES_PER_IMG 3136
#define BLK_HALF 392                   // per (xcd&1) half, per image

typedef float f4 __attribute__((ext_vector_type(4)));
typedef int   i4 __attribute__((ext_vector_type(4)));

__device__ __forceinline__ f4 max4(f4 a, f4 b) {
    f4 r;
    r.x = fmaxf(a.x, b.x); r.y = fmaxf(a.y, b.y);
    r.z = fmaxf(a.z, b.z); r.w = fmaxf(a.w, b.w);
    return r;
}
__device__ __forceinline__ int rfl(int x) { return __builtin_amdgcn_readfirstlane(x); }

// ---- Kernel 1: per-bin descriptor {sbase(pixel idx), npix, wbin, magic}.
// One thread per bin; ROI float4s (512 distinct) are L1/L2-hot. ~3us.
// Removes the s_load-roi -> floorf -> int-div chain from every main wave.
__global__ __launch_bounds__(256) void desc_kernel(
    const float* __restrict__ rois, i4* __restrict__ desc)
{
    const int gbin = blockIdx.x * 256 + threadIdx.x;   // 98*256 = 25088
    const int br  = gbin / (PH * PW);
    const int bin = gbin - br * (PH * PW);
    const int b   = br >> 7;
    const int ph  = bin / PW;
    const int pw  = bin - ph * PW;

    const f4 roi = ((const f4*)rois)[br];
    const int h0 = (int)floorf((float)HH * roi.x);
    const int w0 = (int)floorf((float)WW * roi.y);
    const int h1 = (int)floorf((float)HH * roi.z);
    const int w1 = (int)floorf((float)WW * roi.w);
    const int rh = h1 - h0, rw = w1 - w0;
    const int hstep = max(rh / PH, 1), wstep = max(rw / PW, 1);

    int hs = h0 + ph * hstep;
    int he = (ph == PH - 1) ? (h0 + rh) : (hs + hstep);
    he = min(he, h0 + rh);  he = min(he, HH);
    int ws = w0 + pw * wstep;
    int we = (pw == PW - 1) ? (w0 + rw) : (ws + wstep);
    we = min(we, w0 + rw);  we = min(we, WW);

    const int hbin = he - hs, wbin = we - ws;
    const int npix = (hbin > 0 && wbin > 0) ? hbin * wbin : 0;
    const int wb   = max(wbin, 1);
    i4 d;
    d.x = (b * HH + hs) * WW + ws;                     // base pixel index
    d.y = npix;
    d.z = wb;
    d.w = (int)((65536u + (unsigned)wb - 1) / (unsigned)wb);   // magic
    desc[gbin] = d;
}

// ---- Kernel 2: one wave per TWO bins. Critical path: 2 parallel s_loads
// (L2-hot descriptors) -> 16 loads in flight (8 per bin) -> max trees ->
// 2 NT stores. Clamp-dup pixels idempotent under max; fused loop runs to
// max(npix0,npix1) (extra batches re-load the last pixel: L1-hot, merge is
// idempotent). XCD swizzle: image b -> xcds {2b,2b+1} (R2: FETCH 50->12MB).
__global__ __launch_bounds__(256, 4) void ROIPoolingLayer_62079457296467_kernel(
    const float* __restrict__ fm, const i4* __restrict__ desc,
    float* __restrict__ out)
{
    const int lane = threadIdx.x & 63;
    const int wave = rfl((int)threadIdx.x >> 6);

    // 3136 blocks = 8 xcds x 392; image b = xcd>>1; 784 blocks per image.
    const int bid  = blockIdx.x;
    const int xcd  = bid & 7;
    const int b    = xcd >> 1;
    const int inb  = (xcd & 1) * BLK_HALF + (bid >> 3);     // 0..783
    const int gw   = b * WAVES_PER_IMG + inb * 4 + wave;    // 0..12543
    const int g0   = 2 * gw;                                // bin pair
    const int g1   = g0 + 1;

    const i4 d0 = desc[g0];            // wave-uniform -> s_load_dwordx4
    const i4 d1 = desc[g1];
    const int n0 = rfl(d0.y), n1 = rfl(d1.y);

    const f4* __restrict__ fm4 = (const f4*)fm + lane;
    f4 acc0 = (f4){-INFINITY, -INFINITY, -INFINITY, -INFINITY};
    f4 acc1 = acc0;

    if (n0 > 0 && n1 > 0) {            // always true for this distribution
        const int s0 = rfl(d0.x), w0b = rfl(d0.z);
        const int s1 = rfl(d1.x), w1b = rfl(d1.z);
        const unsigned m0 = (unsigned)rfl(d0.w), m1 = (unsigned)rfl(d1.w);
        const int pmax = max(n0, n1);
        for (int p = 0; p < pmax; p += 8) {
            f4 v0[8], v1[8];
#pragma unroll
            for (int k = 0; k < 8; ++k) {
                const int pk = min(p + k, n0 - 1);
                const int q  = (int)(((unsigned)pk * m0) >> 16);
                const int off = rfl(s0 + q * WW + (pk - q * w0b));
                v0[k] = fm4[(size_t)off * CH4];
            }
#pragma unroll
            for (int k = 0; k < 8; ++k) {
                const int pk = min(p + k, n1 - 1);
                const int q  = (int)(((unsigned)pk * m1) >> 16);
                const int off = rfl(s1 + q * WW + (pk - q * w1b));
                v1[k] = fm4[(size_t)off * CH4];
            }
#pragma unroll
            for (int k = 0; k < 4; ++k) v0[k] = max4(v0[k], v0[k + 4]);
            acc0 = max4(acc0, max4(max4(v0[0], v0[1]), max4(v0[2], v0[3])));
#pragma unroll
            for (int k = 0; k < 4; ++k) v1[k] = max4(v1[k], v1[k + 4]);
            acc1 = max4(acc1, max4(max4(v1[0], v1[1]), max4(v1[2], v1[3])));
        }
    } else {
        // safety path (degenerate bins; not taken for this input range)
        for (int t = 0; t < 2; ++t) {
            const i4 d = t ? d1 : d0;
            const int n = rfl(d.y);
            if (n <= 0) continue;
            const int sb = rfl(d.x), wb = rfl(d.z);
            const unsigned m = (unsigned)rfl(d.w);
            f4 a = (f4){-INFINITY, -INFINITY, -INFINITY, -INFINITY};
            for (int p = 0; p < n; p += 8) {
                f4 v[8];
#pragma unroll
                for (int k = 0; k < 8; ++k) {
                    const int pk = min(p + k, n - 1);
                    const int q  = (int)(((unsigned)pk * m) >> 16);
                    const int off = rfl(sb + q * WW + (pk - q * wb));
                    v[k] = fm4[(size_t)off * CH4];
                }
#pragma unroll
                for (int k = 0; k < 4; ++k) v[k] = max4(v[k], v[k + 4]);
                a = max4(a, max4(max4(v[0], v[1]), max4(v[2], v[3])));
            }
            if (t) acc1 = a; else acc0 = a;
        }
    }

    f4* o = (f4*)out + (size_t)g0 * CH4 + lane;
    __builtin_nontemporal_store(acc0, o);
    __builtin_nontemporal_store(acc1, o + CH4);
}

extern "C" void kernel_launch(void* const* d_in, const int* in_sizes, int n_in,
                              void* d_out, int out_size, void* d_ws, size_t ws_size,
                              hipStream_t stream) {
    const float* fm   = (const float*)d_in[0];
    const float* rois = (const float*)d_in[1];
    float* out        = (float*)d_out;
    i4* desc          = (i4*)d_ws;     // 400 KB << ws_size
    desc_kernel<<<NBINS / 256, 256, 0, stream>>>(rois, desc);
    ROIPoolingLayer_62079457296467_kernel<<<MAIN_BLK, 256, 0, stream>>>(fm, desc, out);
}